// Round 1
// baseline (567.219 us; speedup 1.0000x reference)
//
#include <hip/hip_runtime.h>

#define BATCH 16
#define SEQ   4096
#define HEADS 16
#define EMB   64
#define SS    64      // s = sqrt(SEQ)
#define NW    127     // 2*s - 1

// RxV / RxU workspace arrays: [b][t][h][e] = 16*64*16*64 floats each (4 MB)
#define RX_ELEMS (BATCH * SS * HEADS * EMB)

// ---------------------------------------------------------------------------
// Kernel 1: per (b,h,i-chunk) reduce + partial circular conv, atomic merge.
// Grid: B*H*4 = 1024 blocks, 256 threads (4 waves). Wave w owns 4 rows of the
// 16-row i-chunk in phase 1, and 16 t-values in the conv phase.
// ---------------------------------------------------------------------------
__global__ __launch_bounds__(256, 4) void reduce_conv_kernel(
    const float* __restrict__ v, const float* __restrict__ w,
    float* __restrict__ rxv, float* __restrict__ rxu)
{
    __shared__ float vsf[SS][SS];    // partial v_s for this chunk: [j][e]
    __shared__ float usl[16][SS];    // u_s rows of this chunk:     [r][e]
    __shared__ float wtab[NW];

    const int blk  = blockIdx.x;           // ((b*HEADS + h) << 2) | c
    const int c    = blk & 3;
    const int bh   = blk >> 2;
    const int b    = bh >> 4;
    const int h    = bh & (HEADS - 1);
    const int tid  = threadIdx.x;
    const int wave = tid >> 6;             // 0..3
    const int lane = tid & 63;             // e

    for (int idx = tid; idx < SS * SS; idx += 256) (&vsf[0][0])[idx] = 0.0f;
    if (tid < NW) wtab[tid] = w[h * NW + tid];
    __syncthreads();

    // ---- phase 1: rows i = c*16 .. c*16+15; wave owns 4 of them ----
    const float* vbase = v + ((size_t)b * SEQ * HEADS + h) * EMB + lane;
    float vsacc[SS];
    #pragma unroll
    for (int j = 0; j < SS; ++j) vsacc[j] = 0.0f;

    const int r0 = wave * 4;
    for (int rr = 0; rr < 4; ++rr) {
        const int i = c * 16 + r0 + rr;
        const float* rowp = vbase + (size_t)i * SS * (HEADS * EMB);
        float uacc = 0.0f;
        #pragma unroll
        for (int j = 0; j < SS; ++j) {
            const float val = rowp[(size_t)j * (HEADS * EMB)];
            uacc += val;
            vsacc[j] += val;
        }
        usl[r0 + rr][lane] = uacc;
    }
    // merge per-wave v_s partials (vsf zeroed + synced above)
    #pragma unroll
    for (int j = 0; j < SS; ++j) atomicAdd(&vsf[j][lane], vsacc[j]);
    __syncthreads();

    // ---- phase 2: partial conv. RxV_p[t] = sum_j wtab[(t-j+64)%127]*vsf[j]
    //               RxU_p[t] = sum_r wtab[(t-(c*16+r)+64)%127]*usl[r]
    // wtab accessed through a 31-entry register window per 16x16 (t,j) tile
    // to avoid ~1k LDS broadcast reads per wave.
    const int t0 = wave * 16;
    float accv[16], accu[16];
    #pragma unroll
    for (int tt = 0; tt < 16; ++tt) { accv[tt] = 0.0f; accu[tt] = 0.0f; }

    #pragma unroll
    for (int jb = 0; jb < 4; ++jb) {
        float wreg[31];
        #pragma unroll
        for (int d = 0; d < 31; ++d) {
            int idx = t0 - jb * 16 + 49 + d;   // in [1,127]
            if (idx >= NW) idx -= NW;
            wreg[d] = wtab[idx];
        }
        #pragma unroll
        for (int jj = 0; jj < 16; ++jj) {
            const float cv = vsf[jb * 16 + jj][lane];
            #pragma unroll
            for (int tt = 0; tt < 16; ++tt)
                accv[tt] += wreg[15 + tt - jj] * cv;   // = wtab[(t-j+64)%127]
        }
    }
    {
        float wreg[31];
        #pragma unroll
        for (int d = 0; d < 31; ++d) {
            int idx = t0 - c * 16 + 49 + d;    // in [1,127]
            if (idx >= NW) idx -= NW;
            wreg[d] = wtab[idx];
        }
        #pragma unroll
        for (int rr = 0; rr < 16; ++rr) {
            const float cu = usl[rr][lane];
            #pragma unroll
            for (int tt = 0; tt < 16; ++tt)
                accu[tt] += wreg[15 + tt - rr] * cu;   // = wtab[(t-i'+64)%127]
        }
    }

    // ---- phase 3: merge partial conv results (4 chunks per element) ----
    const size_t base = (((size_t)b * SS) << 10) + (h << 6) + lane;
    #pragma unroll
    for (int tt = 0; tt < 16; ++tt) {
        const size_t o = base + ((size_t)(t0 + tt) << 10);
        atomicAdd(&rxv[o], accv[tt]);
        atomicAdd(&rxu[o], accu[tt]);
    }
}

// ---------------------------------------------------------------------------
// Kernel 2: expand. out[b, i*64+j, h, e] = RxV[b][j][h][e] + RxU[b][i][h][e].
// Grid: B*64 = 1024 blocks (one per (b,i)), 256 threads, float4 everywhere.
// Writes 4 KB contiguous per j; RxV[b] (256 KB) is L2-resident.
// ---------------------------------------------------------------------------
__global__ __launch_bounds__(256) void expand_kernel(
    const float* __restrict__ rxv, const float* __restrict__ rxu,
    float* __restrict__ out)
{
    const int blk = blockIdx.x;        // b*64 + i
    const int b   = blk >> 6;
    const int tid = threadIdx.x;

    const float4 ru = *((const float4*)(rxu + ((size_t)blk << 10)) + tid);
    const float4* rvb = (const float4*)(rxv + ((size_t)b << 16));     // b*65536 floats
    float4* ob = (float4*)(out + (((size_t)blk) << 16)) + tid;        // (b*4096+i*64)*1024

    #pragma unroll 8
    for (int j = 0; j < SS; ++j) {
        float4 rv = rvb[(j << 8) + tid];
        float4 r;
        r.x = rv.x + ru.x; r.y = rv.y + ru.y;
        r.z = rv.z + ru.z; r.w = rv.w + ru.w;
        ob[(size_t)j << 8] = r;
    }
}

// ---------------------------------------------------------------------------
// z_pb: zp[h][t] = s * sum_j o_[j] * w[h, (t-j+64)%127]
// out2[0, i*64+j, h] = zp[h][j] + zp[h][i].  Grid: 64 blocks (one per i).
// ---------------------------------------------------------------------------
__global__ __launch_bounds__(256) void zpb_kernel(const float* __restrict__ w,
                                                  const float* __restrict__ o_,
                                                  float* __restrict__ out2) {
    __shared__ float zp[HEADS][SS];
    __shared__ float osh[SS];
    __shared__ float wsh[HEADS * NW];

    const int tid = threadIdx.x;
    const int g   = blockIdx.x;   // i index

    if (tid < SS) osh[tid] = o_[tid];
    for (int idx = tid; idx < HEADS * NW; idx += 256) wsh[idx] = w[idx];
    __syncthreads();

    for (int idx = tid; idx < HEADS * SS; idx += 256) {
        const int h = idx / SS, t = idx % SS;
        float acc = 0.0f;
        #pragma unroll
        for (int j = 0; j < SS; ++j) {
            int k = t - j + 64;
            if (k >= NW) k -= NW;
            acc += osh[j] * wsh[h * NW + k];
        }
        zp[h][t] = acc * (float)SS;
    }
    __syncthreads();

    for (int idx = tid; idx < SS * HEADS; idx += 256) {
        const int tl = idx / HEADS, h = idx % HEADS;
        out2[(size_t)(g * SS + tl) * HEADS + h] = zp[h][tl] + zp[h][g];
    }
}

extern "C" void kernel_launch(void* const* d_in, const int* in_sizes, int n_in,
                              void* d_out, int out_size, void* d_ws, size_t ws_size,
                              hipStream_t stream) {
    const float* v  = (const float*)d_in[0];
    const float* w  = (const float*)d_in[1];
    const float* o_ = (const float*)d_in[2];
    float* out = (float*)d_out;

    float* rxv = (float*)d_ws;
    float* rxu = rxv + RX_ELEMS;

    // zero the 8 MB RxV/RxU accumulators (graph-capture-safe async memset)
    hipMemsetAsync(d_ws, 0, (size_t)2 * RX_ELEMS * sizeof(float), stream);

    reduce_conv_kernel<<<BATCH * HEADS * 4, 256, 0, stream>>>(v, w, rxv, rxu);
    expand_kernel<<<BATCH * SS, 256, 0, stream>>>(rxv, rxu, out);

    const size_t out1_elems = (size_t)BATCH * SEQ * HEADS * EMB;
    zpb_kernel<<<SS, 256, 0, stream>>>(w, o_, out + out1_elems);
}